// Round 12
// baseline (226.041 us; speedup 1.0000x reference)
//
#include <hip/hip_runtime.h>

#define H      128
#define OBSROW 141
#define GPB    16     // graphs per block (MFMA M dimension)
#define NT     512    // 8 waves = 4 o-pairs x 2 node-halves

typedef __bf16 bf16x8 __attribute__((ext_vector_type(8)));
typedef float  f32x4  __attribute__((ext_vector_type(4)));

__device__ __forceinline__ float eluf(float v) {
    return v > 0.0f ? v : (__expf(v) - 1.0f);
}
__device__ __forceinline__ f32x4 mf(bf16x8 a, bf16x8 b, f32x4 c) {
    return __builtin_amdgcn_mfma_f32_16x16x32_bf16(a, b, c, 0, 0, 0);
}

// ws (bf16 elems): [0)Wrel 3*16384 | [49152)Wroot 3*16384 | [98304)We_b pad[128][64] | [106496)We_j pad[128][32]
#define WS_ROOT 49152
#define WS_EB   98304
#define WS_EJ   106496
#define WS_TOT  110592

__global__ void convert_weights(const float* __restrict__ Wr, const float* __restrict__ Wo,
                                const float* __restrict__ Web, const float* __restrict__ Wej,
                                __bf16* __restrict__ ws) {
    const int i = blockIdx.x * 256 + threadIdx.x;
    if (i < WS_ROOT) {
        ws[i] = (__bf16)Wr[i];
    } else if (i < WS_EB) {
        ws[i] = (__bf16)Wo[i - WS_ROOT];
    } else if (i < WS_EJ) {
        const int j = i - WS_EB, o = j >> 6, f = j & 63;
        ws[i] = (__bf16)(f < 33 ? Web[o*33 + f] : 0.0f);
    } else if (i < WS_TOT) {
        const int j = i - WS_EJ, o = j >> 5, f = j & 31;
        ws[i] = (__bf16)(f < 9 ? Wej[o*9 + f] : 0.0f);
    }
}

// X layout: [node 13][hc=h/8 16][graph 16][hi 8]  (bf16) -> A-frag = 16B contiguous
#define XIDX(n,hc,g,hi) (((((n)*16 + (hc))*16 + (g))*8) + (hi))
// cross-Yrel tiles (f32 C-layout): t 0=y0, 1=y7, 2=y10; per o-pair, per o-tile
#define YCX(t,o2,ot) ((((((t)*4 + (o2))*2 + (ot))*64) + lane)*4)

__launch_bounds__(NT, 4)   // 4 waves/EU -> 128-reg cap; peak demand ~107; 2 blocks/CU
__global__ void gnn_fused(const float* __restrict__ obs,
                          const float* __restrict__ be_b, const float* __restrict__ be_j,
                          const float* __restrict__ b_rel,
                          const float* __restrict__ W_dec, const float* __restrict__ b_dec,
                          const __bf16* __restrict__ wsb,
                          float* __restrict__ out, int B)
{
    __shared__ __align__(16) unsigned short Xs[13*2048];   // 53248 B
    __shared__ __align__(16) float Yc[3*4*2*64*4];         // 24576 B (also obs staging)

    const int tid  = threadIdx.x;
    const int wave = tid >> 6;     // 0..7
    const int op   = wave & 3;     // o-pair 0..3 (o-tiles 2*op, 2*op+1)
    const int half = wave >> 2;    // 0 -> nodes 0..6, 1 -> nodes 7..12
    const int lane = tid & 63;
    const int q    = lane >> 4;    // quad 0..3
    const int c    = lane & 15;    // col-in-tile / graph-in-chunk
    const int g0   = blockIdx.x * GPB;
    const int o0   = op*32 + c;          // o-col of tile 2*op
    const int o1   = o0 + 16;            // o-col of tile 2*op+1

    unsigned short* Fs = (unsigned short*)Yc;   // staging view (14336 B used)

    // ---------------- stage obs features ----------------
    // joints at Fs[jj*512 + fc*128 + g*8 + hi] (jj 0..11, f = fc*8+hi, f<9 valid)
    for (int s = tid; s < 6144; s += NT) {
        const int jj = s >> 9, rem = s & 511;
        const int fc = rem >> 7, g = (rem >> 3) & 15, hi = rem & 7;
        const int f = fc*8 + hi;
        float v = 0.0f;
        if (f < 9 && (g0 + g) < B)
            v = obs[(g0+g)*OBSROW + (f/3)*47 + 9 + (f%3)*12 + jj];
        *(__bf16*)&Fs[s] = (__bf16)v;
    }
    // base at Fs[6144 + fc*128 + g*8 + hi] (f = fc*8+hi, f<33 valid, K padded to 64)
    for (int s = tid; s < 1024; s += NT) {
        const int fc = s >> 7, rem = s & 127, g = rem >> 3, hi = rem & 7;
        const int f = fc*8 + hi;
        float v = 0.0f;
        if (f < 33 && (g0 + g) < B) {
            const int tt = f / 11, i2 = f % 11;   // BASE_IDX[i] = i<9 ? i : 36+i
            v = obs[(g0+g)*OBSROW + tt*47 + (i2 < 9 ? i2 : 36 + i2)];
        }
        *(__bf16*)&Fs[6144 + s] = (__bf16)v;
    }
    __syncthreads();

    const int hi  = c & 7;
    const int hc0 = (op*2+0)*2 + (c >> 3);
    const int hc1 = (op*2+1)*2 + (c >> 3);

    // ---------------- encoders (o-paired: one A-read feeds both o-tiles) ----------------
    if (half == 0) {
        // node 0 (base), K=64 -> 2 MFMAs per o-tile
        const bf16x8 u00 = *(const bf16x8*)(wsb + WS_EB + o0*64 + q*8);
        const bf16x8 u01 = *(const bf16x8*)(wsb + WS_EB + o0*64 + 32 + q*8);
        const bf16x8 u10 = *(const bf16x8*)(wsb + WS_EB + o1*64 + q*8);
        const bf16x8 u11 = *(const bf16x8*)(wsb + WS_EB + o1*64 + 32 + q*8);
        const bf16x8 a0 = *(const bf16x8*)&Fs[6144 + q*128 + c*8];
        const bf16x8 a1 = *(const bf16x8*)&Fs[6144 + 512 + q*128 + c*8];
        const float bb0 = be_b[o0], bb1 = be_b[o1];
        f32x4 e0 = {bb0,bb0,bb0,bb0}, e1 = {bb1,bb1,bb1,bb1};
        e0 = mf(a0, u00, e0); e0 = mf(a1, u01, e0);
        e1 = mf(a0, u10, e1); e1 = mf(a1, u11, e1);
        #pragma unroll
        for (int r = 0; r < 4; r++) {
            *(__bf16*)&Xs[XIDX(0, hc0, q*4 + r, hi)] = (__bf16)eluf(e0[r]);
            *(__bf16*)&Xs[XIDX(0, hc1, q*4 + r, hi)] = (__bf16)eluf(e1[r]);
        }
        // joints 0..5 -> nodes 1..6
        const bf16x8 uj0 = *(const bf16x8*)(wsb + WS_EJ + o0*32 + q*8);
        const bf16x8 uj1 = *(const bf16x8*)(wsb + WS_EJ + o1*32 + q*8);
        const float bj0 = be_j[o0], bj1 = be_j[o1];
        #pragma unroll
        for (int jj = 0; jj < 6; jj++) {
            const bf16x8 a = *(const bf16x8*)&Fs[jj*512 + q*128 + c*8];
            f32x4 c0 = {bj0,bj0,bj0,bj0}, c1 = {bj1,bj1,bj1,bj1};
            c0 = mf(a, uj0, c0); c1 = mf(a, uj1, c1);
            #pragma unroll
            for (int r = 0; r < 4; r++) {
                *(__bf16*)&Xs[XIDX(1+jj, hc0, q*4 + r, hi)] = (__bf16)eluf(c0[r]);
                *(__bf16*)&Xs[XIDX(1+jj, hc1, q*4 + r, hi)] = (__bf16)eluf(c1[r]);
            }
        }
    } else {
        // joints 6..11 -> nodes 7..12
        const bf16x8 uj0 = *(const bf16x8*)(wsb + WS_EJ + o0*32 + q*8);
        const bf16x8 uj1 = *(const bf16x8*)(wsb + WS_EJ + o1*32 + q*8);
        const float bj0 = be_j[o0], bj1 = be_j[o1];
        #pragma unroll
        for (int jj = 6; jj < 12; jj++) {
            const bf16x8 a = *(const bf16x8*)&Fs[jj*512 + q*128 + c*8];
            f32x4 c0 = {bj0,bj0,bj0,bj0}, c1 = {bj1,bj1,bj1,bj1};
            c0 = mf(a, uj0, c0); c1 = mf(a, uj1, c1);
            #pragma unroll
            for (int r = 0; r < 4; r++) {
                *(__bf16*)&Xs[XIDX(1+jj, hc0, q*4 + r, hi)] = (__bf16)eluf(c0[r]);
                *(__bf16*)&Xs[XIDX(1+jj, hc1, q*4 + r, hi)] = (__bf16)eluf(c1[r]);
            }
        }
    }
    __syncthreads();

    // ---------------- 3 GraphConv layers (2 barriers each) ----------------
    const unsigned short* xr = Xs + q*128 + c*8;   // A-frag(n,k) at xr + n*2048 + k*512
    const int cnt = half ? 6 : 7;

    #pragma unroll 1
    for (int l = 0; l < 3; l++) {
        const __bf16* wr0 = wsb + l*16384 + o0*128 + q*8;
        const __bf16* wr1 = wsb + l*16384 + o1*128 + q*8;
        const __bf16* wo0 = wsb + WS_ROOT + l*16384 + o0*128 + q*8;
        const __bf16* wo1 = wsb + WS_ROOT + l*16384 + o1*128 + q*8;
        const float bias0 = b_rel[l*H + o0];
        const float bias1 = b_rel[l*H + o1];

        f32x4 acc[7][2];
        #pragma unroll
        for (int i = 0; i < 7; i++) {       // pre-init to bias (free bias add)
            acc[i][0] = (f32x4){bias0,bias0,bias0,bias0};
            acc[i][1] = (f32x4){bias1,bias1,bias1,bias1};
        }
        f32x4 yca[2] = {{0.f,0.f,0.f,0.f},{0.f,0.f,0.f,0.f}};  // y0 (h0) / y7 (h1)
        f32x4 ycb[2] = {{0.f,0.f,0.f,0.f},{0.f,0.f,0.f,0.f}};  // --   / y10 (h1)

        // cross node: rel accumulates in ycross regs; root into acc[l]
        #define CNODEA(n, ll) { \
            const bf16x8 xa = *(const bf16x8*)(xk + (n)*2048); \
            yca[0] = mf(xa, br0, yca[0]); yca[1] = mf(xa, br1, yca[1]); \
            acc[ll][0] = mf(xa, bo0, acc[ll][0]); acc[ll][1] = mf(xa, bo1, acc[ll][1]); }
        #define CNODEB(n, ll) { \
            const bf16x8 xa = *(const bf16x8*)(xk + (n)*2048); \
            ycb[0] = mf(xa, br0, ycb[0]); ycb[1] = mf(xa, br1, ycb[1]); \
            acc[ll][0] = mf(xa, bo0, acc[ll][0]); acc[ll][1] = mf(xa, bo1, acc[ll][1]); }
        // simple node: transient y scattered to 1-2 local dsts
        #define SNODE2(n, ll, la, lb) { \
            const bf16x8 xa = *(const bf16x8*)(xk + (n)*2048); \
            f32x4 t0 = {0.f,0.f,0.f,0.f}, t1 = {0.f,0.f,0.f,0.f}; \
            t0 = mf(xa, br0, t0); t1 = mf(xa, br1, t1); \
            acc[ll][0] = mf(xa, bo0, acc[ll][0]); acc[ll][1] = mf(xa, bo1, acc[ll][1]); \
            acc[la][0] += t0; acc[la][1] += t1; acc[lb][0] += t0; acc[lb][1] += t1; }
        #define SNODE1(n, ll, la) { \
            const bf16x8 xa = *(const bf16x8*)(xk + (n)*2048); \
            f32x4 t0 = {0.f,0.f,0.f,0.f}, t1 = {0.f,0.f,0.f,0.f}; \
            t0 = mf(xa, br0, t0); t1 = mf(xa, br1, t1); \
            acc[ll][0] = mf(xa, bo0, acc[ll][0]); acc[ll][1] = mf(xa, bo1, acc[ll][1]); \
            acc[la][0] += t0; acc[la][1] += t1; }

        #pragma unroll 1
        for (int k = 0; k < 4; k++) {
            const bf16x8 br0 = *(const bf16x8*)(wr0 + k*32);
            const bf16x8 br1 = *(const bf16x8*)(wr1 + k*32);
            const bf16x8 bo0 = *(const bf16x8*)(wo0 + k*32);
            const bf16x8 bo1 = *(const bf16x8*)(wo1 + k*32);
            const unsigned short* xk = xr + k*512;
            if (half == 0) {
                CNODEA(0, 0);              // node 0: y0 cross, dsts 1,4 deferred
                SNODE2(1, 1, 0, 2);
                SNODE2(2, 2, 1, 3);
                SNODE1(3, 3, 2);
                SNODE2(4, 4, 0, 5);
                SNODE2(5, 5, 4, 6);
                SNODE1(6, 6, 5);
            } else {
                CNODEA(7, 0);              // y7 cross; dst 8 deferred
                CNODEB(10, 3);             // y10 cross; dst 11 deferred
                SNODE2(8, 1, 0, 2);
                SNODE1(9, 2, 1);
                SNODE2(11, 4, 3, 5);
                SNODE1(12, 5, 4);
            }
        }
        #undef CNODEA
        #undef CNODEB
        #undef SNODE2
        #undef SNODE1

        // deferred intra adds from cross accumulators + publish cross tiles
        if (half == 0) {
            acc[1][0] += yca[0]; acc[1][1] += yca[1];   // node 1 <- y0
            acc[4][0] += yca[0]; acc[4][1] += yca[1];   // node 4 <- y0
            *(f32x4*)&Yc[YCX(0, op, 0)] = yca[0];
            *(f32x4*)&Yc[YCX(0, op, 1)] = yca[1];
        } else {
            acc[1][0] += yca[0]; acc[1][1] += yca[1];   // node 8  <- y7
            acc[4][0] += ycb[0]; acc[4][1] += ycb[1];   // node 11 <- y10
            *(f32x4*)&Yc[YCX(1, op, 0)] = yca[0];
            *(f32x4*)&Yc[YCX(1, op, 1)] = yca[1];
            *(f32x4*)&Yc[YCX(2, op, 0)] = ycb[0];
            *(f32x4*)&Yc[YCX(2, op, 1)] = ycb[1];
        }
        __syncthreads();   // cross tiles visible; all X reads drained

        if (half == 0) {
            acc[0][0] += *(const f32x4*)&Yc[YCX(1, op, 0)] + *(const f32x4*)&Yc[YCX(2, op, 0)];
            acc[0][1] += *(const f32x4*)&Yc[YCX(1, op, 1)] + *(const f32x4*)&Yc[YCX(2, op, 1)];
        } else {
            const f32x4 y00 = *(const f32x4*)&Yc[YCX(0, op, 0)];
            const f32x4 y01 = *(const f32x4*)&Yc[YCX(0, op, 1)];
            acc[0][0] += y00; acc[0][1] += y01;   // node 7  <- y0
            acc[3][0] += y00; acc[3][1] += y01;   // node 10 <- y0
        }
        // epilogue: elu (bias pre-added), write new X in place
        {
            const int n0g = half*7;
            #pragma unroll
            for (int i = 0; i < 7; i++) {
                if (i < cnt) {
                    const int n = n0g + i;
                    #pragma unroll
                    for (int r = 0; r < 4; r++) {
                        *(__bf16*)&Xs[XIDX(n, hc0, q*4 + r, hi)] = (__bf16)eluf(acc[i][0][r]);
                        *(__bf16*)&Xs[XIDX(n, hc1, q*4 + r, hi)] = (__bf16)eluf(acc[i][1][r]);
                    }
                }
            }
        }
        __syncthreads();   // new X visible; Yc free for next layer
    }

    // ---------------- decoder: out[g][j] = x[j+1]·W_dec + b_dec ----------------
    {
        // decoder base: hc = q*4 + hq  ->  h = q*32 + hq*8 + hi (matches wd indexing)
        const unsigned short* xdec = Xs + q*512 + c*8;
        float wd[32];
        #pragma unroll
        for (int i4 = 0; i4 < 8; i4++) {
            const float4 wv = *(const float4*)&W_dec[q*32 + i4*4];
            wd[i4*4+0] = wv.x; wd[i4*4+1] = wv.y; wd[i4*4+2] = wv.z; wd[i4*4+3] = wv.w;
        }
        const float bd = b_dec[0];
        for (int j = wave; j < 12; j += 8) {    // waves 0..3 do two joints, 4..7 one
            float s = 0.0f;
            #pragma unroll
            for (int hq = 0; hq < 4; hq++) {    // lane covers h = q*32 + hq*8 + hi
                const bf16x8 xv = *(const bf16x8*)(xdec + (j+1)*2048 + hq*128);
                #pragma unroll
                for (int hi2 = 0; hi2 < 8; hi2++)
                    s += (float)xv[hi2] * wd[hq*8 + hi2];
            }
            s += __shfl_xor(s, 16);
            s += __shfl_xor(s, 32);
            if (q == 0 && (g0 + c) < B)
                out[(g0 + c)*12 + j] = s + bd;
        }
    }
}

extern "C" void kernel_launch(void* const* d_in, const int* in_sizes, int n_in,
                              void* d_out, int out_size, void* d_ws, size_t ws_size,
                              hipStream_t stream) {
    const float* obs   = (const float*)d_in[0];
    const float* We_b  = (const float*)d_in[1];
    const float* be_b  = (const float*)d_in[2];
    const float* We_j  = (const float*)d_in[3];
    const float* be_j  = (const float*)d_in[4];
    const float* W_rel = (const float*)d_in[5];
    const float* W_root= (const float*)d_in[6];
    const float* b_rel = (const float*)d_in[7];
    const float* W_dec = (const float*)d_in[8];
    const float* b_dec = (const float*)d_in[9];
    // d_in[10]/d_in[11] (src/dst) are the fixed tree edges; adjacency is baked in.
    float* out = (float*)d_out;
    __bf16* wsb = (__bf16*)d_ws;   // 221 KB of bf16 weights

    const int B = in_sizes[0] / OBSROW;
    convert_weights<<<(WS_TOT + 255) / 256, 256, 0, stream>>>(W_rel, W_root, We_b, We_j, wsb);
    const int blocks = (B + GPB - 1) / GPB;
    gnn_fused<<<blocks, NT, 0, stream>>>(obs, be_b, be_j, b_rel, W_dec, b_dec,
                                         wsb, out, B);
}

// Round 13
// 200.849 us; speedup vs baseline: 1.1254x; 1.1254x over previous
//
#include <hip/hip_runtime.h>

#define H      128
#define OBSROW 141
#define GPB    16     // graphs per block (MFMA M dimension)
#define NT     512    // 8 waves = 8 o-tiles; each wave owns all 13 nodes

typedef __bf16 bf16x8 __attribute__((ext_vector_type(8)));
typedef float  f32x4  __attribute__((ext_vector_type(4)));

__device__ __forceinline__ float eluf(float v) {
    return v > 0.0f ? v : (__expf(v) - 1.0f);
}
__device__ __forceinline__ f32x4 mf(bf16x8 a, bf16x8 b, f32x4 c) {
    return __builtin_amdgcn_mfma_f32_16x16x32_bf16(a, b, c, 0, 0, 0);
}

// ws (bf16 elems): [0)Wrel 3*16384 | [49152)Wroot 3*16384 | [98304)We_b pad[128][64] | [106496)We_j pad[128][32]
#define WS_ROOT 49152
#define WS_EB   98304
#define WS_EJ   106496
#define WS_TOT  110592

__global__ void convert_weights(const float* __restrict__ Wr, const float* __restrict__ Wo,
                                const float* __restrict__ Web, const float* __restrict__ Wej,
                                __bf16* __restrict__ ws) {
    const int i = blockIdx.x * 256 + threadIdx.x;
    if (i < WS_ROOT) {
        ws[i] = (__bf16)Wr[i];
    } else if (i < WS_EB) {
        ws[i] = (__bf16)Wo[i - WS_ROOT];
    } else if (i < WS_EJ) {
        const int j = i - WS_EB, o = j >> 6, f = j & 63;
        ws[i] = (__bf16)(f < 33 ? Web[o*33 + f] : 0.0f);
    } else if (i < WS_TOT) {
        const int j = i - WS_EJ, o = j >> 5, f = j & 31;
        ws[i] = (__bf16)(f < 9 ? Wej[o*9 + f] : 0.0f);
    }
}

// X layout: [node 13][hc=h/8 16][graph 16][hi 8]  (bf16) -> A-frag = 16B contiguous
#define XIDX(n,hc,g,hi) (((((n)*16 + (hc))*16 + (g))*8) + (hi))

__launch_bounds__(NT, 4)   // 4 waves/EU -> 128-reg cap; peak demand ~95; 2 blocks/CU
__global__ void gnn_fused(const float* __restrict__ obs,
                          const float* __restrict__ be_b, const float* __restrict__ be_j,
                          const float* __restrict__ b_rel,
                          const float* __restrict__ W_dec, const float* __restrict__ b_dec,
                          const __bf16* __restrict__ wsb,
                          float* __restrict__ out, int B)
{
    __shared__ __align__(16) unsigned short Xs[13*2048];   // 53248 B (single buffer)
    __shared__ __align__(16) unsigned short Fs[7168];      // 14336 B feature staging

    const int tid  = threadIdx.x;
    const int wave = tid >> 6;     // 0..7 == o-tile
    const int lane = tid & 63;
    const int q    = lane >> 4;    // quad 0..3
    const int c    = lane & 15;    // col-in-tile / graph-in-chunk
    const int g0   = blockIdx.x * GPB;
    const int jt   = wave;
    const int o    = jt*16 + c;

    // out-neighbor adjacency of the undirected tree (scatter targets)
    static constexpr int ODEG[13]    = {4,2,2,1,2,2,1,2,2,1,2,2,1};
    static constexpr int ODST[13][4] = {
        {1,4,7,10},{0,2,0,0},{1,3,0,0},{2,0,0,0},{0,5,0,0},{4,6,0,0},{5,0,0,0},
        {0,8,0,0},{7,9,0,0},{8,0,0,0},{0,11,0,0},{10,12,0,0},{11,0,0,0}};

    // ---------------- stage 0: COALESCED obs copy global -> LDS raw (in Xs area) ----
    // thread i <-> consecutive dword: fully coalesced. raw[g][col], 16x141 f32 = 9024 B.
    {
        float* raw = (float*)Xs;
        for (int i = tid; i < GPB*OBSROW; i += NT) {
            const int g = i / OBSROW, col = i - g*OBSROW;
            raw[i] = ((g0 + g) < B) ? obs[(g0+g)*OBSROW + col] : 0.0f;
            (void)col;
        }
    }
    __syncthreads();

    // ---------------- stage 1: gather + cvt LDS raw -> Fs (bank-speed scatter) ------
    {
        const float* raw = (const float*)Xs;
        // joints at Fs[jj*512 + fc*128 + g*8 + hi] (jj 0..11, f = fc*8+hi, f<9 valid)
        for (int s = tid; s < 6144; s += NT) {
            const int jj = s >> 9, rem = s & 511;
            const int fc = rem >> 7, g = (rem >> 3) & 15, hi = rem & 7;
            const int f = fc*8 + hi;
            float v = 0.0f;
            if (f < 9)
                v = raw[g*OBSROW + (f/3)*47 + 9 + (f%3)*12 + jj];
            *(__bf16*)&Fs[s] = (__bf16)v;
        }
        // base at Fs[6144 + fc*128 + g*8 + hi] (f = fc*8+hi, f<33 valid, K padded to 64)
        for (int s = tid; s < 1024; s += NT) {
            const int fc = s >> 7, rem = s & 127, g = rem >> 3, hi = rem & 7;
            const int f = fc*8 + hi;
            float v = 0.0f;
            if (f < 33) {
                const int tt = f / 11, i2 = f % 11;   // BASE_IDX[i] = i<9 ? i : 36+i
                v = raw[g*OBSROW + tt*47 + (i2 < 9 ? i2 : 36 + i2)];
            }
            *(__bf16*)&Fs[6144 + s] = (__bf16)v;
        }
    }
    __syncthreads();

    // ---------------- encoders (each wave: full 13 nodes for its o-tile) ----------------
    {   // node 0 (base), K=64 -> 2 MFMAs
        const bf16x8 u0 = *(const bf16x8*)(wsb + WS_EB + o*64 + q*8);
        const bf16x8 u1 = *(const bf16x8*)(wsb + WS_EB + o*64 + 32 + q*8);
        const bf16x8 a0 = *(const bf16x8*)&Fs[6144 + q*128 + c*8];
        const bf16x8 a1 = *(const bf16x8*)&Fs[6144 + 512 + q*128 + c*8];
        const float bias = be_b[o];
        f32x4 acc = {bias, bias, bias, bias};
        acc = mf(a0, u0, acc);
        acc = mf(a1, u1, acc);
        #pragma unroll
        for (int r = 0; r < 4; r++)
            *(__bf16*)&Xs[XIDX(0, jt*2 + (c>>3), q*4 + r, c & 7)] = (__bf16)eluf(acc[r]);
    }
    {   // joints 0..11, K=32 -> 1 MFMA each
        const bf16x8 uj = *(const bf16x8*)(wsb + WS_EJ + o*32 + q*8);
        const float bias = be_j[o];
        #pragma unroll
        for (int jj = 0; jj < 12; jj++) {
            const bf16x8 a = *(const bf16x8*)&Fs[jj*512 + q*128 + c*8];
            f32x4 acc = {bias, bias, bias, bias};
            acc = mf(a, uj, acc);
            #pragma unroll
            for (int r = 0; r < 4; r++)
                *(__bf16*)&Xs[XIDX(1+jj, jt*2 + (c>>3), q*4 + r, c & 7)] = (__bf16)eluf(acc[r]);
        }
    }
    __syncthreads();

    // ---------------- 3 GraphConv layers ----------------
    // Streaming scatter: acc[13] persists (bias-preinit); per node y is transient
    // and scattered immediately. K split in halves so only 4 B-frags live.
    const unsigned short* xr = Xs + q*128 + c*8;   // A-frag(n,k) at xr + n*2048 + k*512
    #pragma unroll 1
    for (int l = 0; l < 3; l++) {
        const __bf16* wr = wsb + l*16384 + o*128 + q*8;
        const __bf16* wo = wsb + WS_ROOT + l*16384 + o*128 + q*8;
        const float bias = b_rel[l*H + o];

        f32x4 acc[13];
        #pragma unroll
        for (int n = 0; n < 13; n++) acc[n] = (f32x4){bias, bias, bias, bias};

        #pragma unroll 1
        for (int h = 0; h < 2; h++) {
            const bf16x8 br0 = *(const bf16x8*)(wr + (2*h+0)*32);
            const bf16x8 br1 = *(const bf16x8*)(wr + (2*h+1)*32);
            const bf16x8 bo0 = *(const bf16x8*)(wo + (2*h+0)*32);
            const bf16x8 bo1 = *(const bf16x8*)(wo + (2*h+1)*32);
            const unsigned short* xh = xr + 2*h*512;
            #pragma unroll
            for (int n = 0; n < 13; n++) {
                const bf16x8 xa0 = *(const bf16x8*)(xh + n*2048);
                const bf16x8 xa1 = *(const bf16x8*)(xh + n*2048 + 512);
                // root contribution straight into acc[n]
                acc[n] = mf(xa0, bo0, acc[n]);
                acc[n] = mf(xa1, bo1, acc[n]);
                // rel contribution into transient y, then scatter to neighbors
                f32x4 y = {0.f,0.f,0.f,0.f};
                y = mf(xa0, br0, y);
                y = mf(xa1, br1, y);
                #pragma unroll
                for (int e = 0; e < 4; e++)
                    if (e < ODEG[n]) acc[ODST[n][e]] += y;
            }
        }
        __syncthreads();   // all X reads done
        // ---- epilogue: elu (bias pre-added) + cvt, write new X in place
        {
            const int hc = jt*2 + (c >> 3);
            const int hi = c & 7;
            #pragma unroll
            for (int n = 0; n < 13; n++) {
                #pragma unroll
                for (int r = 0; r < 4; r++)
                    *(__bf16*)&Xs[XIDX(n, hc, q*4 + r, hi)] = (__bf16)eluf(acc[n][r]);
            }
        }
        __syncthreads();   // new X visible
    }

    // ---------------- decoder: out[g][j] = x[j+1]·W_dec + b_dec ----------------
    {
        // decoder base: hc = q*4 + hq  ->  h = q*32 + hq*8 + hi (matches wd indexing)
        const unsigned short* xdec = Xs + q*512 + c*8;
        float wd[32];
        #pragma unroll
        for (int i4 = 0; i4 < 8; i4++) {
            const float4 wv = *(const float4*)&W_dec[q*32 + i4*4];
            wd[i4*4+0] = wv.x; wd[i4*4+1] = wv.y; wd[i4*4+2] = wv.z; wd[i4*4+3] = wv.w;
        }
        const float bd = b_dec[0];
        for (int j = wave; j < 12; j += 8) {    // waves 0..3 do two joints, 4..7 one
            float s = 0.0f;
            #pragma unroll
            for (int hq = 0; hq < 4; hq++) {    // lane covers h = q*32 + hq*8 + hi
                const bf16x8 xv = *(const bf16x8*)(xdec + (j+1)*2048 + hq*128);
                #pragma unroll
                for (int hi2 = 0; hi2 < 8; hi2++)
                    s += (float)xv[hi2] * wd[hq*8 + hi2];
            }
            s += __shfl_xor(s, 16);
            s += __shfl_xor(s, 32);
            if (q == 0 && (g0 + c) < B)
                out[(g0 + c)*12 + j] = s + bd;
        }
    }
}

extern "C" void kernel_launch(void* const* d_in, const int* in_sizes, int n_in,
                              void* d_out, int out_size, void* d_ws, size_t ws_size,
                              hipStream_t stream) {
    const float* obs   = (const float*)d_in[0];
    const float* We_b  = (const float*)d_in[1];
    const float* be_b  = (const float*)d_in[2];
    const float* We_j  = (const float*)d_in[3];
    const float* be_j  = (const float*)d_in[4];
    const float* W_rel = (const float*)d_in[5];
    const float* W_root= (const float*)d_in[6];
    const float* b_rel = (const float*)d_in[7];
    const float* W_dec = (const float*)d_in[8];
    const float* b_dec = (const float*)d_in[9];
    // d_in[10]/d_in[11] (src/dst) are the fixed tree edges; adjacency is baked in.
    float* out = (float*)d_out;
    __bf16* wsb = (__bf16*)d_ws;   // 221 KB of bf16 weights

    const int B = in_sizes[0] / OBSROW;
    convert_weights<<<(WS_TOT + 255) / 256, 256, 0, stream>>>(W_rel, W_root, We_b, We_j, wsb);
    const int blocks = (B + GPB - 1) / GPB;
    gnn_fused<<<blocks, NT, 0, stream>>>(obs, be_b, be_j, b_rel, W_dec, b_dec,
                                         wsb, out, B);
}